// Round 4
// baseline (305.578 us; speedup 1.0000x reference)
//
#include <hip/hip_runtime.h>

// Problem constants: B=16, S=2048, D=1024, P=8192, R=16, NL=64, span<=31
#define S_LEN      2048
#define D_DIM      1024
#define R_DIM      16
#define OUT_STRIDE 2064          // 2*D + R
#define NKEYS      32768         // B * S_LEN flat row keys
#define GROUP      8             // sorted jobs per gather block

// ---------------------------------------------------------------------------
// Counting sort of the 2P span-jobs by flat start row (b*S + s).
// ws layout: [0,128KB) int cursor[NKEYS]; [128KB,192KB) int sorted[2P]

__global__ __launch_bounds__(256) void zero_hist(int* __restrict__ h) {
    h[blockIdx.x * 256 + threadIdx.x] = 0;
}

__global__ __launch_bounds__(256) void hist_jobs(
    const int* __restrict__ bidx, const int* __restrict__ e1s,
    const int* __restrict__ e2s, int* __restrict__ hist, int njobs)
{
    const int j = blockIdx.x * 256 + threadIdx.x;
    if (j >= njobs) return;
    const int p = j >> 1;
    const int s = (j & 1) ? e2s[p] : e1s[p];
    atomicAdd(hist + bidx[p] * S_LEN + s, 1);
}

// single block, 1024 threads, 32 keys/thread: exclusive scan of NKEYS counts
__global__ __launch_bounds__(1024) void scan_hist(int* __restrict__ hist) {
    __shared__ int lds[1024];
    const int t = threadIdx.x;
    int v[32];
    int sum = 0;
#pragma unroll
    for (int i = 0; i < 32; ++i) { v[i] = hist[t * 32 + i]; sum += v[i]; }
    lds[t] = sum;
    __syncthreads();
    for (int off = 1; off < 1024; off <<= 1) {   // Hillis-Steele inclusive
        int x = (t >= off) ? lds[t - off] : 0;
        __syncthreads();
        lds[t] += x;
        __syncthreads();
    }
    int run = (t == 0) ? 0 : lds[t - 1];
#pragma unroll
    for (int i = 0; i < 32; ++i) { int c = v[i]; hist[t * 32 + i] = run; run += c; }
}

__global__ __launch_bounds__(256) void scatter_jobs(
    const int* __restrict__ bidx, const int* __restrict__ e1s,
    const int* __restrict__ e2s, int* __restrict__ cursor,
    int* __restrict__ sorted, int njobs)
{
    const int j = blockIdx.x * 256 + threadIdx.x;
    if (j >= njobs) return;
    const int p = j >> 1;
    const int s = (j & 1) ? e2s[p] : e1s[p];
    const int pos = atomicAdd(cursor + bidx[p] * S_LEN + s, 1);
    sorted[pos] = j;
}

// ---------------------------------------------------------------------------
// Grouped gather: block g handles sorted jobs [8g, 8g+8). Their start rows are
// nearly consecutive (avg gap ~2 rows, spans ~16 rows) so one shared window of
// ~30 rows covers all 8 spans. Read the window ONCE, accumulate 8 span sums in
// registers. Spans never cross a batch boundary (e <= s+31 <= 2046), so flat
// row indexing b*S+s is exact. Job descriptors are forced into SGPRs
// (readfirstlane) -> in-range tests compile to scalar branches, no divergence.
__global__ __launch_bounds__(256) void gather_grouped(
    const float* __restrict__ tok,     // [B*S, D] fp32
    const int*   __restrict__ sorted,  // [2P] sorted job ids
    const int*   __restrict__ bidx,
    const int*   __restrict__ e1s, const int* __restrict__ e1e,
    const int*   __restrict__ e2s, const int* __restrict__ e2e,
    const int*   __restrict__ ridx,
    const float* __restrict__ rtab,    // [NL, R]
    float*       __restrict__ out)     // [P, 2D+R]
{
    const int g = blockIdx.x;
    const int t = threadIdx.x;         // lane owns cols [4t, 4t+4)

    int jp[GROUP], jh[GROUP], js[GROUP], je[GROUP];
    int mins = 0x7fffffff, maxe = 0;
#pragma unroll
    for (int i = 0; i < GROUP; ++i) {
        const int id = __builtin_amdgcn_readfirstlane(sorted[g * GROUP + i]);
        const int p  = id >> 1;
        const int h  = id & 1;
        const int b  = __builtin_amdgcn_readfirstlane(bidx[p]);
        const int s  = __builtin_amdgcn_readfirstlane(h ? e2s[p] : e1s[p]);
        const int e  = __builtin_amdgcn_readfirstlane(h ? e2e[p] : e1e[p]);
        jp[i] = p; jh[i] = h;
        js[i] = b * S_LEN + s;
        je[i] = b * S_LEN + e;
        mins  = min(mins, js[i]);
        maxe  = max(maxe, je[i]);
    }

    float4 acc[GROUP];
#pragma unroll
    for (int i = 0; i < GROUP; ++i) acc[i] = make_float4(0.f, 0.f, 0.f, 0.f);

    const float4* src = reinterpret_cast<const float4*>(tok) +
                        (size_t)mins * (D_DIM / 4) + t;
    for (int r = mins; r < maxe; ++r) {
        const float4 v = *src;
        src += D_DIM / 4;
#pragma unroll
        for (int i = 0; i < GROUP; ++i) {
            if (r >= js[i] && r < je[i]) {   // wave-uniform -> scalar branch
                acc[i].x += v.x; acc[i].y += v.y;
                acc[i].z += v.z; acc[i].w += v.w;
            }
        }
    }

#pragma unroll
    for (int i = 0; i < GROUP; ++i) {
        const float inv = 1.0f / (float)(je[i] - js[i]);
        const float4 o = make_float4(acc[i].x * inv, acc[i].y * inv,
                                     acc[i].z * inv, acc[i].w * inv);
        float* dst = out + (size_t)jp[i] * OUT_STRIDE + jh[i] * D_DIM + t * 4;
        *reinterpret_cast<float4*>(dst) = o;
        // rel row once per pair (on the half-0 job)
        if (jh[i] == 0 && t < 4) {
            const float4 rv = *reinterpret_cast<const float4*>(
                rtab + ridx[jp[i]] * R_DIM + t * 4);
            *reinterpret_cast<float4*>(
                out + (size_t)jp[i] * OUT_STRIDE + 2 * D_DIM + t * 4) = rv;
        }
    }
}

// ---------------------------------------------------------------------------
extern "C" void kernel_launch(void* const* d_in, const int* in_sizes, int n_in,
                              void* d_out, int out_size, void* d_ws, size_t ws_size,
                              hipStream_t stream) {
    const float* tok  = (const float*)d_in[0];
    const int*   bidx = (const int*)d_in[1];
    const int*   e1s  = (const int*)d_in[2];
    const int*   e1e  = (const int*)d_in[3];
    const int*   e2s  = (const int*)d_in[4];
    const int*   e2e  = (const int*)d_in[5];
    const int*   ridx = (const int*)d_in[6];
    const float* rtab = (const float*)d_in[7];
    float*       out  = (float*)d_out;

    const int P     = in_sizes[1];   // 8192
    const int njobs = 2 * P;         // 16384

    int* cursor = (int*)d_ws;                       // NKEYS ints
    int* sorted = (int*)d_ws + NKEYS;               // njobs ints

    zero_hist<<<NKEYS / 256, 256, 0, stream>>>(cursor);
    hist_jobs<<<(njobs + 255) / 256, 256, 0, stream>>>(bidx, e1s, e2s, cursor, njobs);
    scan_hist<<<1, 1024, 0, stream>>>(cursor);
    scatter_jobs<<<(njobs + 255) / 256, 256, 0, stream>>>(bidx, e1s, e2s, cursor,
                                                          sorted, njobs);
    gather_grouped<<<njobs / GROUP, 256, 0, stream>>>(
        tok, sorted, bidx, e1s, e1e, e2s, e2e, ridx, rtab, out);
}

// Round 5
// 267.193 us; speedup vs baseline: 1.1437x; 1.1437x over previous
//
#include <hip/hip_runtime.h>

// Problem constants: B=16, S=2048, D=1024, P=8192, R=16, NL=64, span<=31
#define S_LEN      2048
#define D_DIM      1024
#define R_DIM      16
#define OUT_STRIDE 2064          // 2*D + R
#define NKEYS      32768         // B * S_LEN flat row keys
#define GROUP      8             // sorted jobs per gather block

// ---------------------------------------------------------------------------
// Counting sort of the 2P span-jobs by flat start row (b*S + s).
// ws layout: [0,128KB) int cursor[NKEYS]; [128KB,192KB) int sorted[2P]

__global__ __launch_bounds__(256) void zero_hist(int* __restrict__ h) {
    h[blockIdx.x * 256 + threadIdx.x] = 0;
}

__global__ __launch_bounds__(256) void hist_jobs(
    const int* __restrict__ bidx, const int* __restrict__ e1s,
    const int* __restrict__ e2s, int* __restrict__ hist, int njobs)
{
    const int j = blockIdx.x * 256 + threadIdx.x;
    if (j >= njobs) return;
    const int p = j >> 1;
    const int s = (j & 1) ? e2s[p] : e1s[p];
    atomicAdd(hist + bidx[p] * S_LEN + s, 1);
}

// single block, 1024 threads, 32 keys/thread: exclusive scan of NKEYS counts
__global__ __launch_bounds__(1024) void scan_hist(int* __restrict__ hist) {
    __shared__ int lds[1024];
    const int t = threadIdx.x;
    int v[32];
    int sum = 0;
#pragma unroll
    for (int i = 0; i < 32; ++i) { v[i] = hist[t * 32 + i]; sum += v[i]; }
    lds[t] = sum;
    __syncthreads();
    for (int off = 1; off < 1024; off <<= 1) {   // Hillis-Steele inclusive
        int x = (t >= off) ? lds[t - off] : 0;
        __syncthreads();
        lds[t] += x;
        __syncthreads();
    }
    int run = (t == 0) ? 0 : lds[t - 1];
#pragma unroll
    for (int i = 0; i < 32; ++i) { int c = v[i]; hist[t * 32 + i] = run; run += c; }
}

__global__ __launch_bounds__(256) void scatter_jobs(
    const int* __restrict__ bidx, const int* __restrict__ e1s,
    const int* __restrict__ e2s, int* __restrict__ cursor,
    int* __restrict__ sorted, int njobs)
{
    const int j = blockIdx.x * 256 + threadIdx.x;
    if (j >= njobs) return;
    const int p = j >> 1;
    const int s = (j & 1) ? e2s[p] : e1s[p];
    const int pos = atomicAdd(cursor + bidx[p] * S_LEN + s, 1);
    sorted[pos] = j;
}

// ---------------------------------------------------------------------------
// Grouped gather v2: branch-free weighted accumulation, 4-row unroll.
// Block g handles sorted jobs [8g, 8g+8) over one shared row window read ONCE.
// Weight w_i(r) = inv_len_i if r in span_i else 0 — selected via wave-uniform
// scalar compares (descriptors in SGPRs), consumed by v_fma. No control flow
// in the hot body -> loads pipeline 4+ deep.
__global__ __launch_bounds__(256) void gather_grouped2(
    const float* __restrict__ tok,     // [B*S, D] fp32
    const int*   __restrict__ sorted,  // [2P] sorted job ids
    const int*   __restrict__ bidx,
    const int*   __restrict__ e1s, const int* __restrict__ e1e,
    const int*   __restrict__ e2s, const int* __restrict__ e2e,
    const int*   __restrict__ ridx,
    const float* __restrict__ rtab,    // [NL, R]
    float*       __restrict__ out)     // [P, 2D+R]
{
    const int g0 = blockIdx.x;
    // XCD swizzle: blocks round-robin XCDs by blockIdx%8; give each XCD a
    // CONTIGUOUS range of sorted groups so its L2 sees a sliding row window.
    const int g  = (g0 & 7) * (gridDim.x >> 3) + (g0 >> 3);
    const int t  = threadIdx.x;        // lane owns cols [4t, 4t+4)

    int   jp[GROUP], jh[GROUP], js[GROUP], je[GROUP];
    float jw[GROUP];
    int mins = 0x7fffffff, maxe = 0;
#pragma unroll
    for (int i = 0; i < GROUP; ++i) {
        const int id = __builtin_amdgcn_readfirstlane(sorted[g * GROUP + i]);
        const int p  = id >> 1;
        const int h  = id & 1;
        const int b  = __builtin_amdgcn_readfirstlane(bidx[p]);
        const int s  = __builtin_amdgcn_readfirstlane(h ? e2s[p] : e1s[p]);
        const int e  = __builtin_amdgcn_readfirstlane(h ? e2e[p] : e1e[p]);
        jp[i] = p; jh[i] = h;
        js[i] = b * S_LEN + s;
        je[i] = b * S_LEN + e;
        jw[i] = 1.0f / (float)(e - s);
        mins  = min(mins, js[i]);
        maxe  = max(maxe, je[i]);
    }

    float4 acc[GROUP];
#pragma unroll
    for (int i = 0; i < GROUP; ++i) acc[i] = make_float4(0.f, 0.f, 0.f, 0.f);

    const float4* base = reinterpret_cast<const float4*>(tok) +
                         (size_t)mins * (D_DIM / 4) + t;
    const int nrows = maxe - mins;

    int r = 0;
    for (; r + 4 <= nrows; r += 4) {           // 4 loads in flight, no branches
        const float4 v0 = base[(size_t)(r + 0) * (D_DIM / 4)];
        const float4 v1 = base[(size_t)(r + 1) * (D_DIM / 4)];
        const float4 v2 = base[(size_t)(r + 2) * (D_DIM / 4)];
        const float4 v3 = base[(size_t)(r + 3) * (D_DIM / 4)];
        const int rr = mins + r;
#pragma unroll
        for (int i = 0; i < GROUP; ++i) {
            const float w0 = (rr + 0 >= js[i] && rr + 0 < je[i]) ? jw[i] : 0.f;
            const float w1 = (rr + 1 >= js[i] && rr + 1 < je[i]) ? jw[i] : 0.f;
            const float w2 = (rr + 2 >= js[i] && rr + 2 < je[i]) ? jw[i] : 0.f;
            const float w3 = (rr + 3 >= js[i] && rr + 3 < je[i]) ? jw[i] : 0.f;
            acc[i].x += v0.x * w0 + v1.x * w1 + v2.x * w2 + v3.x * w3;
            acc[i].y += v0.y * w0 + v1.y * w1 + v2.y * w2 + v3.y * w3;
            acc[i].z += v0.z * w0 + v1.z * w1 + v2.z * w2 + v3.z * w3;
            acc[i].w += v0.w * w0 + v1.w * w1 + v2.w * w2 + v3.w * w3;
        }
    }
    for (; r < nrows; ++r) {                   // <=3 tail rows
        const float4 v = base[(size_t)r * (D_DIM / 4)];
        const int rr = mins + r;
#pragma unroll
        for (int i = 0; i < GROUP; ++i) {
            const float w = (rr >= js[i] && rr < je[i]) ? jw[i] : 0.f;
            acc[i].x += v.x * w; acc[i].y += v.y * w;
            acc[i].z += v.z * w; acc[i].w += v.w * w;
        }
    }

#pragma unroll
    for (int i = 0; i < GROUP; ++i) {
        float* dst = out + (size_t)jp[i] * OUT_STRIDE + jh[i] * D_DIM + t * 4;
        *reinterpret_cast<float4*>(dst) = acc[i];
        if (jh[i] == 0 && t < 4) {             // rel row once per pair
            const float4 rv = *reinterpret_cast<const float4*>(
                rtab + ridx[jp[i]] * R_DIM + t * 4);
            *reinterpret_cast<float4*>(
                out + (size_t)jp[i] * OUT_STRIDE + 2 * D_DIM + t * 4) = rv;
        }
    }
}

// ---------------------------------------------------------------------------
extern "C" void kernel_launch(void* const* d_in, const int* in_sizes, int n_in,
                              void* d_out, int out_size, void* d_ws, size_t ws_size,
                              hipStream_t stream) {
    const float* tok  = (const float*)d_in[0];
    const int*   bidx = (const int*)d_in[1];
    const int*   e1s  = (const int*)d_in[2];
    const int*   e1e  = (const int*)d_in[3];
    const int*   e2s  = (const int*)d_in[4];
    const int*   e2e  = (const int*)d_in[5];
    const int*   ridx = (const int*)d_in[6];
    const float* rtab = (const float*)d_in[7];
    float*       out  = (float*)d_out;

    const int P     = in_sizes[1];   // 8192
    const int njobs = 2 * P;         // 16384

    int* cursor = (int*)d_ws;                       // NKEYS ints
    int* sorted = (int*)d_ws + NKEYS;               // njobs ints

    zero_hist<<<NKEYS / 256, 256, 0, stream>>>(cursor);
    hist_jobs<<<(njobs + 255) / 256, 256, 0, stream>>>(bidx, e1s, e2s, cursor, njobs);
    scan_hist<<<1, 1024, 0, stream>>>(cursor);
    scatter_jobs<<<(njobs + 255) / 256, 256, 0, stream>>>(bidx, e1s, e2s, cursor,
                                                          sorted, njobs);
    gather_grouped2<<<njobs / GROUP, 256, 0, stream>>>(
        tok, sorted, bidx, e1s, e1e, e2s, e2e, ridx, rtab, out);
}

// Round 6
// 265.401 us; speedup vs baseline: 1.1514x; 1.0068x over previous
//
#include <hip/hip_runtime.h>

// Problem constants: B=16, S=2048, D=1024, P=8192, R=16, NL=64, span<=31
#define S_LEN      2048
#define D_DIM      1024
#define R_DIM      16
#define OUT_STRIDE 2064          // 2*D + R
#define NKEYS      32768         // B * S_LEN flat row keys
#define GROUP      8             // sorted jobs per gather group

// ---------------------------------------------------------------------------
// Counting sort of the 2P span-jobs by flat start row (b*S + s).
// ws layout: [0,128KB) int cursor[NKEYS]; [128KB,192KB) int sorted[2P]

__global__ __launch_bounds__(256) void zero_hist(int* __restrict__ h) {
    h[blockIdx.x * 256 + threadIdx.x] = 0;
}

__global__ __launch_bounds__(256) void hist_jobs(
    const int* __restrict__ bidx, const int* __restrict__ e1s,
    const int* __restrict__ e2s, int* __restrict__ hist, int njobs)
{
    const int j = blockIdx.x * 256 + threadIdx.x;
    if (j >= njobs) return;
    const int p = j >> 1;
    const int s = (j & 1) ? e2s[p] : e1s[p];
    atomicAdd(hist + bidx[p] * S_LEN + s, 1);
}

// single block, 1024 threads, 32 keys/thread: exclusive scan of NKEYS counts
__global__ __launch_bounds__(1024) void scan_hist(int* __restrict__ hist) {
    __shared__ int lds[1024];
    const int t = threadIdx.x;
    int v[32];
    int sum = 0;
#pragma unroll
    for (int i = 0; i < 32; ++i) { v[i] = hist[t * 32 + i]; sum += v[i]; }
    lds[t] = sum;
    __syncthreads();
    for (int off = 1; off < 1024; off <<= 1) {   // Hillis-Steele inclusive
        int x = (t >= off) ? lds[t - off] : 0;
        __syncthreads();
        lds[t] += x;
        __syncthreads();
    }
    int run = (t == 0) ? 0 : lds[t - 1];
#pragma unroll
    for (int i = 0; i < 32; ++i) { int c = v[i]; hist[t * 32 + i] = run; run += c; }
}

__global__ __launch_bounds__(256) void scatter_jobs(
    const int* __restrict__ bidx, const int* __restrict__ e1s,
    const int* __restrict__ e2s, int* __restrict__ cursor,
    int* __restrict__ sorted, int njobs)
{
    const int j = blockIdx.x * 256 + threadIdx.x;
    if (j >= njobs) return;
    const int p = j >> 1;
    const int s = (j & 1) ? e2s[p] : e1s[p];
    const int pos = atomicAdd(cursor + bidx[p] * S_LEN + s, 1);
    sorted[pos] = j;
}

// ---------------------------------------------------------------------------
// Grouped gather v3: 128-thread blocks over a 512-col slice (grid = 2 blocks
// per job-group -> 4096 blocks, finer load balance), branch-free weighted
// accumulation, explicit 4-row double-buffered prefetch (loads for rows r+4..
// r+7 issue before rows r..r+3 are consumed), clamped addresses instead of a
// tail loop (out-of-window rows get weight 0).
__global__ __launch_bounds__(128) void gather_grouped3(
    const float* __restrict__ tok,     // [B*S, D] fp32
    const int*   __restrict__ sorted,  // [2P] sorted job ids
    const int*   __restrict__ bidx,
    const int*   __restrict__ e1s, const int* __restrict__ e1e,
    const int*   __restrict__ e2s, const int* __restrict__ e2e,
    const int*   __restrict__ ridx,
    const float* __restrict__ rtab,    // [NL, R]
    float*       __restrict__ out)     // [P, 2D+R]
{
    const int blk = blockIdx.x;
    // XCD swizzle: give each XCD a CONTIGUOUS range of work units so its L2
    // sees a sliding row window.
    const int w  = (blk & 7) * (gridDim.x >> 3) + (blk >> 3);
    const int g  = w >> 1;            // job group (8 sorted jobs)
    const int ch = w & 1;             // column half: cols [ch*512, ch*512+512)
    const int t  = threadIdx.x;       // 128 threads x 4 cols = 512 cols

    int   jp[GROUP], jh[GROUP], js[GROUP], je[GROUP];
    float jw[GROUP];
    int mins = 0x7fffffff, maxe = 0;
#pragma unroll
    for (int i = 0; i < GROUP; ++i) {
        const int id = __builtin_amdgcn_readfirstlane(sorted[g * GROUP + i]);
        const int p  = id >> 1;
        const int h  = id & 1;
        const int b  = __builtin_amdgcn_readfirstlane(bidx[p]);
        const int s  = __builtin_amdgcn_readfirstlane(h ? e2s[p] : e1s[p]);
        const int e  = __builtin_amdgcn_readfirstlane(h ? e2e[p] : e1e[p]);
        jp[i] = p; jh[i] = h;
        js[i] = b * S_LEN + s;
        je[i] = b * S_LEN + e;
        jw[i] = 1.0f / (float)(e - s);
        mins  = min(mins, js[i]);
        maxe  = max(maxe, je[i]);
    }

    float4 acc[GROUP];
#pragma unroll
    for (int i = 0; i < GROUP; ++i) acc[i] = make_float4(0.f, 0.f, 0.f, 0.f);

    // row stride = D/4 = 256 float4; this block's slice starts at ch*128 + t
    const float4* base = reinterpret_cast<const float4*>(tok) +
                         (size_t)mins * (D_DIM / 4) + ch * 128 + t;
    const int nrows = maxe - mins;          // >= 1 always
    const int rmax  = nrows - 1;
    const int niter = (nrows + 3) >> 2;

    float4 cur[4];
#pragma unroll
    for (int k = 0; k < 4; ++k)
        cur[k] = base[(size_t)min(k, rmax) * (D_DIM / 4)];

    for (int it = 0; it < niter; ++it) {
        const int r0 = it * 4;
        float4 nxt[4];                      // prefetch next 4 rows (clamped)
#pragma unroll
        for (int k = 0; k < 4; ++k)
            nxt[k] = base[(size_t)min(r0 + 4 + k, rmax) * (D_DIM / 4)];

        const int gr = mins + r0;           // global row of cur[0]
#pragma unroll
        for (int i = 0; i < GROUP; ++i) {   // weights: wave-uniform scalar sel
            const float w0 = (gr + 0 >= js[i] && gr + 0 < je[i]) ? jw[i] : 0.f;
            const float w1 = (gr + 1 >= js[i] && gr + 1 < je[i]) ? jw[i] : 0.f;
            const float w2 = (gr + 2 >= js[i] && gr + 2 < je[i]) ? jw[i] : 0.f;
            const float w3 = (gr + 3 >= js[i] && gr + 3 < je[i]) ? jw[i] : 0.f;
            acc[i].x += cur[0].x * w0 + cur[1].x * w1 + cur[2].x * w2 + cur[3].x * w3;
            acc[i].y += cur[0].y * w0 + cur[1].y * w1 + cur[2].y * w2 + cur[3].y * w3;
            acc[i].z += cur[0].z * w0 + cur[1].z * w1 + cur[2].z * w2 + cur[3].z * w3;
            acc[i].w += cur[0].w * w0 + cur[1].w * w1 + cur[2].w * w2 + cur[3].w * w3;
        }
#pragma unroll
        for (int k = 0; k < 4; ++k) cur[k] = nxt[k];
    }

#pragma unroll
    for (int i = 0; i < GROUP; ++i) {
        float* dst = out + (size_t)jp[i] * OUT_STRIDE + jh[i] * D_DIM +
                     ch * 512 + t * 4;
        *reinterpret_cast<float4*>(dst) = acc[i];
        if (ch == 0 && jh[i] == 0 && t < 4) {   // rel row once per pair
            const float4 rv = *reinterpret_cast<const float4*>(
                rtab + ridx[jp[i]] * R_DIM + t * 4);
            *reinterpret_cast<float4*>(
                out + (size_t)jp[i] * OUT_STRIDE + 2 * D_DIM + t * 4) = rv;
        }
    }
}

// ---------------------------------------------------------------------------
extern "C" void kernel_launch(void* const* d_in, const int* in_sizes, int n_in,
                              void* d_out, int out_size, void* d_ws, size_t ws_size,
                              hipStream_t stream) {
    const float* tok  = (const float*)d_in[0];
    const int*   bidx = (const int*)d_in[1];
    const int*   e1s  = (const int*)d_in[2];
    const int*   e1e  = (const int*)d_in[3];
    const int*   e2s  = (const int*)d_in[4];
    const int*   e2e  = (const int*)d_in[5];
    const int*   ridx = (const int*)d_in[6];
    const float* rtab = (const float*)d_in[7];
    float*       out  = (float*)d_out;

    const int P     = in_sizes[1];   // 8192
    const int njobs = 2 * P;         // 16384

    int* cursor = (int*)d_ws;                       // NKEYS ints
    int* sorted = (int*)d_ws + NKEYS;               // njobs ints

    zero_hist<<<NKEYS / 256, 256, 0, stream>>>(cursor);
    hist_jobs<<<(njobs + 255) / 256, 256, 0, stream>>>(bidx, e1s, e2s, cursor, njobs);
    scan_hist<<<1, 1024, 0, stream>>>(cursor);
    scatter_jobs<<<(njobs + 255) / 256, 256, 0, stream>>>(bidx, e1s, e2s, cursor,
                                                          sorted, njobs);
    const int nblocks = (njobs / GROUP) * 2;        // 2 col-slices per group
    gather_grouped3<<<nblocks, 128, 0, stream>>>(
        tok, sorted, bidx, e1s, e1e, e2s, e2e, ridx, rtab, out);
}